// Round 17
// baseline (304.187 us; speedup 1.0000x reference)
//
#include <hip/hip_runtime.h>
#include <stdint.h>

// Qwen2 attention layer: B=1, S=2048, H=4096, NH=32, NKV=4, HD=128, causal GQA + RoPE.
// Pipeline: cvt_all(fp32->bf16) -> QKV gemm (128x160, 512 blocks = 2/CU, relaxed
//           1-barrier/tile, column-affine XCD swizzle) -> RoPE (q scaled log2e/sqrt(128))
//           -> V transpose -> flash attention (QBLK=128, native-exp2 no-max softmax,
//           KV-split) -> reduce -> O gemm (128x128, 512 blocks = 2/CU, fp32 out).

using bf16x8 = __attribute__((ext_vector_type(8))) short;          // MFMA A/B frag (8 bf16, 4 VGPR)
using f32x4  = __attribute__((ext_vector_type(4))) float;          // MFMA C/D frag
using u16    = unsigned short;
using u16x4  = __attribute__((ext_vector_type(4))) unsigned short; // 8B store
using u16x8  = __attribute__((ext_vector_type(8))) unsigned short; // 16B copy type

#define S_TOK   2048
#define HID     4096
#define QKV_N   5120   // 4096 q + 512 k + 512 v
#define K_OFF   4096
#define V_OFF   4608
#define NHEAD   32
#define NKVH    4

__device__ __forceinline__ float bf2f(u16 u) {
  unsigned v = ((unsigned)u) << 16;
  return __builtin_bit_cast(float, v);
}
__device__ __forceinline__ u16 f2bf(float f) {   // round-to-nearest-even
  unsigned u = __builtin_bit_cast(unsigned, f);
  u += 0x7fffu + ((u >> 16) & 1u);
  return (u16)(u >> 16);
}

// ---------------- fused fp32 -> bf16 convert for all 5 inputs (grid-stride) ----------------
__global__ void cvt_all_kernel(const float* __restrict__ hs, const float* __restrict__ qw,
                               const float* __restrict__ kw, const float* __restrict__ vw,
                               const float* __restrict__ ow,
                               u16* __restrict__ xbf, u16* __restrict__ wqkv,
                               u16* __restrict__ owbf) {
  const int nHS = 2097152, nQW = 4194304, nKW = 524288, nVW = 524288, nOW = 4194304;
  const int total = nHS + nQW + nKW + nVW + nOW;   // x4 fp32 elements
  int stride = gridDim.x * blockDim.x;
  for (int i = blockIdx.x * blockDim.x + threadIdx.x; i < total; i += stride) {
    const float* s; u16* d; int j = i;
    if (j < nHS) { s = hs; d = xbf; }
    else {
      j -= nHS;
      if (j < nQW) { s = qw; d = wqkv; }
      else {
        j -= nQW;
        if (j < nKW) { s = kw; d = wqkv + 16777216; }
        else {
          j -= nKW;
          if (j < nVW) { s = vw; d = wqkv + 18874368; }
          else { j -= nVW; s = ow; d = owbf; }
        }
      }
    }
    f32x4 v = ((const f32x4*)s)[j];
    union { u16 a[4]; unsigned long long ll; } o;
    o.a[0] = f2bf(v[0]); o.a[1] = f2bf(v[1]); o.a[2] = f2bf(v[2]); o.a[3] = f2bf(v[3]);
    ((unsigned long long*)d)[j] = o.ll;
  }
}

// ---------------- bias concat (q_b | k_b | v_b) -> fp32[5120] ----------------
__global__ void biascat_kernel(const float* __restrict__ qb, const float* __restrict__ kb,
                               const float* __restrict__ vb, float* __restrict__ out) {
  int i = blockIdx.x * 256 + threadIdx.x;
  if (i >= QKV_N) return;
  float v;
  if (i < K_OFF) v = qb[i];
  else if (i < V_OFF) v = kb[i - K_OFF];
  else v = vb[i - V_OFF];
  out[i] = v;
}

// ---------------- async global->LDS (16B per lane, dest = wave base + lane*16) ----------------
__device__ __forceinline__ void gload_lds16(const void* g, void* l) {
  __builtin_amdgcn_global_load_lds(
      (const __attribute__((address_space(1))) void*)g,
      (__attribute__((address_space(3))) void*)l, 16, 0, 0);
}

// ---------------- QKV GEMM: BM=128, BN=160, 256 thr, grid 512 blocks = 2/CU ----
// 4 waves (2m x 2n), per-wave C 64x80 (4mi x 5nf). LDS 72 KB = A[2][16KB] + B[2][20KB]
// -> exactly 2 blocks/CU: the two blocks' barrier phases drift, so one block's LDS-read
// phase overlaps the other's MFMA phase (R13-validated on the O-gemm, +30%).
// Relaxed 1-barrier/tile; stage A(t+1),B(t+1) at tile-t start into buf^1 (WAR-safe:
// buf^1 reads closed at t-1's end barrier); end-of-tile vmcnt(0) = one tile of slack.
// Column-affine XCD swizzle: each XCD owns 4 consecutive bx (B panels ~5.2 MB).
__global__ __launch_bounds__(256, 2)
void gemm_qkv_kernel(const u16* __restrict__ A, const u16* __restrict__ Bm,
                     u16* __restrict__ C, const float* __restrict__ bias,
                     int M, int N, int K) {
  __shared__ __align__(16) u16 LA[2][8192];    // [2 dbuf][128*64]  32 KB
  __shared__ __align__(16) u16 LB[2][10240];   // [2 dbuf][160*64]  40 KB
  const int tid = threadIdx.x;
  const int w = tid >> 6, lane = tid & 63;     // w in 0..3
  const int lg = lane >> 4, l15 = lane & 15;
  const int wm = w >> 1, wn = w & 1;

  // bijective column-affine XCD swizzle (nwg = 512, gridDim.y = 16)
  const int nwg  = gridDim.x * gridDim.y;
  const int orig = blockIdx.y * gridDim.x + blockIdx.x;
  const int cpx  = nwg >> 3;
  const int swz  = (orig & 7) * cpx + (orig >> 3);
  const int by   = swz % gridDim.y, bx = swz / gridDim.y;
  const int m0 = by * 128, n0 = bx * 160;
  const int NT = K >> 6;

  // staging: 1KB chunks (8 rows of 128B); wave w handles chunk (j*4 + w);
  // A: 16 chunks (j 0..3), B: 20 chunks (j 0..4). Source slot pre-swizzled.
  const int  srow  = w * 8 + (lane >> 3);
  const int  sslot = (lane & 7) ^ ((lane >> 3) & 7);
  const u16* As = A  + (size_t)(m0 + srow) * K + sslot * 8;
  const u16* Bs = Bm + (size_t)(n0 + srow) * K + sslot * 8;
  const int  dofs = w * 1024;

  auto stageA = [&](int buf, int t) {
#pragma unroll
    for (int j = 0; j < 4; ++j)
      gload_lds16(As + (size_t)(j * 32) * K + t * 64,
                  (char*)&LA[buf][0] + j * 4096 + dofs);
  };
  auto stageB = [&](int buf, int t) {
#pragma unroll
    for (int j = 0; j < 5; ++j)
      gload_lds16(Bs + (size_t)(j * 32) * K + t * 64,
                  (char*)&LB[buf][0] + j * 4096 + dofs);
  };

  const int rsw = (l15 & 7) << 4;
  auto ldA = [&](int buf, int kk, bf16x8 (&a)[4]) {
#pragma unroll
    for (int mi = 0; mi < 4; ++mi)
      a[mi] = *(const bf16x8*)((const char*)&LA[buf][0]
              + (wm * 64 + mi * 16 + l15) * 128
              + ((kk * 64 + lg * 16) ^ rsw));
  };
  auto ldB = [&](int buf, int kk, bf16x8 (&b)[5]) {
#pragma unroll
    for (int nf = 0; nf < 5; ++nf)
      b[nf] = *(const bf16x8*)((const char*)&LB[buf][0]
              + (wn * 80 + nf * 16 + l15) * 128
              + ((kk * 64 + lg * 16) ^ rsw));
  };

  f32x4 acc[4][5] = {};
  bf16x8 a[4], b[5];

  auto mfma20 = [&]() {
#pragma unroll
    for (int mi = 0; mi < 4; ++mi)
#pragma unroll
      for (int nf = 0; nf < 5; ++nf)
        acc[mi][nf] = __builtin_amdgcn_mfma_f32_16x16x32_bf16(a[mi], b[nf], acc[mi][nf], 0, 0, 0);
  };

  // prologue: tile 0 -> buf 0
  stageA(0, 0); stageB(0, 0);
  asm volatile("s_waitcnt vmcnt(0)" ::: "memory");
  __builtin_amdgcn_s_barrier();

  for (int t = 0; t < NT; ++t) {
    const int buf = t & 1;
    ldA(buf, 0, a);
    ldB(buf, 0, b);
    if (t + 1 < NT) { stageA(buf ^ 1, t + 1); stageB(buf ^ 1, t + 1); }
    mfma20();
    ldA(buf, 1, a);
    ldB(buf, 1, b);
    mfma20();
    asm volatile("s_waitcnt vmcnt(0)" ::: "memory");   // tile t+1 landed
    __builtin_amdgcn_s_barrier();
  }

  // epilogue: D layout col=lane&15, row=(lane>>4)*4+reg  [m89-verified]
#pragma unroll
  for (int mi = 0; mi < 4; ++mi)
#pragma unroll
    for (int nf = 0; nf < 5; ++nf) {
      const int row0 = m0 + wm * 64 + mi * 16 + lg * 4;
      const int cc   = n0 + wn * 80 + nf * 16 + l15;
      const float bv = bias[cc];
#pragma unroll
      for (int rI = 0; rI < 4; ++rI)
        C[(size_t)(row0 + rI) * N + cc] = f2bf(acc[mi][nf][rI] + bv);
    }
}

// ---------------- O GEMM: BM=128, BN=128, 256 thr, grid 512 blocks = 2/CU (R13/R16) ----
template <int BF16OUT>
__global__ __launch_bounds__(256, 2)
void gemm128_kernel(const u16* __restrict__ A, const u16* __restrict__ Bm,
                    void* __restrict__ C, int M, int N, int K) {
  __shared__ __align__(16) u16 LA[2][8192];    // [2 dbuf][128*64]  32 KB
  __shared__ __align__(16) u16 LB[3][8192];    // [3 dbuf][128*64]  48 KB
  const int tid = threadIdx.x;
  const int w = tid >> 6, lane = tid & 63;     // w in 0..3
  const int lg = lane >> 4, l15 = lane & 15;
  const int wm = w >> 1, wn = w & 1;

  const int nwg  = gridDim.x * gridDim.y;      // 512
  const int orig = blockIdx.y * gridDim.x + blockIdx.x;
  const int cpx  = nwg >> 3;
  const int swz  = (orig & 7) * cpx + (orig >> 3);
  const int by   = swz % gridDim.y, bx = swz / gridDim.y;   // column-affine per XCD
  const int m0 = by * 128, n0 = bx * 128;
  const int NT = K >> 6;

  const int  srow  = w * 16 + (lane >> 3);
  const int  sslot = (lane & 7) ^ ((lane >> 3) & 7);
  const u16* As = A  + (size_t)(m0 + srow) * K + sslot * 8;
  const u16* Bs = Bm + (size_t)(n0 + srow) * K + sslot * 8;
  const int  dofs = w * 2048;

  auto stageA = [&](int buf, int t) {
#pragma unroll
    for (int j = 0; j < 2; ++j)
#pragma unroll
      for (int sub = 0; sub < 2; ++sub)
        gload_lds16(As + (size_t)(j * 64 + sub * 8) * K + t * 64,
                    (char*)&LA[buf][0] + j * 8192 + dofs + sub * 1024);
  };
  auto stageB = [&](int buf, int t) {
#pragma unroll
    for (int j = 0; j < 2; ++j)
#pragma unroll
      for (int sub = 0; sub < 2; ++sub)
        gload_lds16(Bs + (size_t)(j * 64 + sub * 8) * K + t * 64,
                    (char*)&LB[buf][0] + j * 8192 + dofs + sub * 1024);
  };

  const int rsw = (l15 & 7) << 4;
  auto ldA = [&](int buf, bf16x8 (&a)[2][4]) {
#pragma unroll
    for (int kk = 0; kk < 2; ++kk)
#pragma unroll
      for (int mi = 0; mi < 4; ++mi)
        a[kk][mi] = *(const bf16x8*)((const char*)&LA[buf][0]
                    + (wm * 64 + mi * 16 + l15) * 128
                    + ((kk * 64 + lg * 16) ^ rsw));
  };
  auto ldB = [&](int buf, bf16x8 (&b)[2][4]) {
#pragma unroll
    for (int kk = 0; kk < 2; ++kk)
#pragma unroll
      for (int nf = 0; nf < 4; ++nf)
        b[kk][nf] = *(const bf16x8*)((const char*)&LB[buf][0]
                    + (wn * 64 + nf * 16 + l15) * 128
                    + ((kk * 64 + lg * 16) ^ rsw));
  };

  f32x4 acc[4][4] = {};   // [mi][nf]
  bf16x8 a[2][4], b[2][4];

  auto mfma32 = [&]() {
#pragma unroll
    for (int kk = 0; kk < 2; ++kk)
#pragma unroll
      for (int mi = 0; mi < 4; ++mi)
#pragma unroll
        for (int nf = 0; nf < 4; ++nf)
          acc[mi][nf] = __builtin_amdgcn_mfma_f32_16x16x32_bf16(a[kk][mi], b[kk][nf], acc[mi][nf], 0, 0, 0);
  };

  stageA(0, 0); stageB(0, 0);
  stageA(1, 1); stageB(1, 1);
  asm volatile("s_waitcnt vmcnt(8)" ::: "memory");
  __builtin_amdgcn_s_barrier();

  for (int t = 0; t < NT; ++t) {
    const int bufA = t & 1, bufB = t % 3;
    ldA(bufA, a);
    ldB(bufB, b);
    if (t > 0 && t + 1 < NT) stageA((t + 1) & 1, t + 1);
    if (t + 2 < NT)          stageB((t + 2) % 3, t + 2);
    mfma32();
    if (t >= NT - 2) asm volatile("s_waitcnt vmcnt(0)" ::: "memory");
    else             asm volatile("s_waitcnt vmcnt(4)" ::: "memory");
    __builtin_amdgcn_s_barrier();
  }

#pragma unroll
  for (int mi = 0; mi < 4; ++mi)
#pragma unroll
    for (int nf = 0; nf < 4; ++nf) {
      const int row0 = m0 + wm * 64 + mi * 16 + lg * 4;
      const int cc   = n0 + wn * 64 + nf * 16 + l15;
#pragma unroll
      for (int rI = 0; rI < 4; ++rI) {
        float v = acc[mi][nf][rI];
        if (BF16OUT) ((u16*)C)[(size_t)(row0 + rI) * N + cc] = f2bf(v);
        else         ((float*)C)[(size_t)(row0 + rI) * N + cc] = v;
      }
    }
}

// ---------------- RoPE in-place; q scale = log2(e)/sqrt(128) (for exp2 softmax) ----------
__global__ void rope_kernel(u16* __restrict__ qkv, const int* __restrict__ pos_ids) {
  const int tid  = threadIdx.x;
  const int gid  = blockIdx.x * 4 + (tid >> 6);   // (s, head) pair; 2048*36 total
  const int lane = tid & 63;                       // d in [0,64)
  const int s = gid / 36, hh = gid - s * 36;       // hh: 0..31 q heads, 32..35 k heads
  const float pos = (float)pos_ids[s];
  const float inv = exp2f((float)lane * -0.20762050593f);  // 10000^(-d/64)
  float sn, cs;
  sincosf(pos * inv, &sn, &cs);
  size_t base = (size_t)s * QKV_N + (hh < 32 ? hh * 128 : K_OFF + (hh - 32) * 128);
  float x1 = bf2f(qkv[base + lane]);
  float x2 = bf2f(qkv[base + lane + 64]);
  float o1 = x1 * cs - x2 * sn;
  float o2 = x2 * cs + x1 * sn;
  if (hh < 32) { o1 *= 0.12751743f; o2 *= 0.12751743f; }  // log2e / sqrt(128)
  qkv[base + lane]      = f2bf(o1);
  qkv[base + lane + 64] = f2bf(o2);
}

// ---------------- V transpose: qkv v-cols [2048][512] -> vt [512][2048] ----------------
__global__ void vtrans_kernel(const u16* __restrict__ qkv, u16* __restrict__ vt) {
  __shared__ u16 t[32][33];
  const int tx = threadIdx.x & 31, ty = threadIdx.x >> 5;  // 32x8
  const int bc = blockIdx.x;  // 16 col tiles (512/32)
  const int bs = blockIdx.y;  // 64 row tiles (2048/32)
#pragma unroll
  for (int i = 0; i < 4; ++i)
    t[ty + i * 8][tx] = qkv[(size_t)(bs * 32 + ty + i * 8) * QKV_N + V_OFF + bc * 32 + tx];
  __syncthreads();
#pragma unroll
  for (int i = 0; i < 4; ++i)
    vt[(size_t)(bc * 32 + ty + i * 8) * S_TOK + bs * 32 + tx] = t[tx][ty + i * 8];
}

// ---------------- Flash attention: QBLK=128, native-exp2 no-max softmax, KV-split ----------
__global__ __launch_bounds__(256, 2)
void attn_kernel(const u16* __restrict__ qkv, const u16* __restrict__ vt,
                 u16* __restrict__ aout, float* __restrict__ Opart,
                 float* __restrict__ Lpart) {
  __shared__ __align__(16) u16 Kl[2][64 * 128];   // K tile, rows 256B, chunk-swizzled
  __shared__ __align__(16) u16 Vl[2][128 * 64];   // V^T tile, rows 128B, chunk-swizzled
  __shared__ __align__(16) u16 Pl[4][32 * 64];    // per-wave P (32x64), rows 128B
  const int tid = threadIdx.x, wave = tid >> 6, lane = tid & 63;
  const int lg = lane >> 4, l15 = lane & 15;

  const int bid  = blockIdx.x;
  const int xcd  = bid & 7;
  const int idx  = bid >> 3;
  const int kvh  = xcd >> 1;
  const int item = idx * 2 + (xcd & 1);
  const int h    = (kvh << 3) + item / 24;
  const int r    = item % 24;

  int qt, t0, t1, cpart;
  bool diag;
  if (r < 8)       { qt = r;     t0 = 0;  t1 = 2 * r + 1;  cpart = -1; diag = true;  }
  else if (r < 16) { qt = r;     t0 = 0;  t1 = 15;         cpart = 0;  diag = false; }
  else             { qt = r - 8; t0 = 16; t1 = 2 * qt + 1; cpart = 1;  diag = true;  }
  const int q0 = qt * 128;

  bf16x8 qf[2][4];
#pragma unroll
  for (int mf = 0; mf < 2; ++mf) {
    const u16* qp = qkv + (size_t)(q0 + wave * 32 + mf * 16 + l15) * QKV_N + h * 128 + lg * 8;
#pragma unroll
    for (int kk = 0; kk < 4; ++kk) qf[mf][kk] = *(const bf16x8*)(qp + kk * 32);
  }

  const u16* kp[4];
  const u16* vp[4];
  const int kc0 = wave * 4;
#pragma unroll
  for (int i = 0; i < 4; ++i) {
    int krow = (kc0 + i) * 4 + (lane >> 4);
    int kch  = lane & 15;
    kp[i] = qkv + K_OFF + kvh * 128 + (size_t)krow * QKV_N + ((kch ^ (krow & 7)) * 8);
    int vrow = (kc0 + i) * 8 + (lane >> 3);     // d index 0..127
    int vch  = lane & 7;
    vp[i] = vt + (size_t)(kvh * 128 + vrow) * S_TOK + ((vch ^ (vrow & 7)) * 8);
  }

  f32x4 o[2][8];
#pragma unroll
  for (int mf = 0; mf < 2; ++mf)
#pragma unroll
    for (int i = 0; i < 8; ++i) o[mf][i] = f32x4{0.f, 0.f, 0.f, 0.f};
  float lsum[2][4] = {};

#pragma unroll
  for (int i = 0; i < 4; ++i) {
    gload_lds16(kp[i] + (size_t)t0 * 64 * QKV_N, &Kl[t0 & 1][(kc0 + i) * 512]);
    gload_lds16(vp[i] + t0 * 64,                 &Vl[t0 & 1][(kc0 + i) * 512]);
  }
  __syncthreads();

  for (int t = t0; t <= t1; ++t) {
    const int cur = t & 1;
    if (t < t1) {
      const size_t koff = (size_t)(t + 1) * 64 * QKV_N;
      const int    voff = (t + 1) * 64;
#pragma unroll
      for (int i = 0; i < 4; ++i) {
        gload_lds16(kp[i] + koff, &Kl[cur ^ 1][(kc0 + i) * 512]);
        gload_lds16(vp[i] + voff, &Vl[cur ^ 1][(kc0 + i) * 512]);
      }
    }
    const int kv0 = t * 64;
    const bool dg = diag && (t >= 2 * qt);   // last two tiles straddle the diagonal

    f32x4 s0[4], s1[4];
#pragma unroll
    for (int jb = 0; jb < 4; ++jb) {
      int j = jb * 16 + l15;
      const char* kb = (const char*)&Kl[cur][0] + j * 256;
      int swzk = (j & 7) << 4;
      bf16x8 kf[4];
#pragma unroll
      for (int kk = 0; kk < 4; ++kk)
        kf[kk] = *(const bf16x8*)(kb + (((kk * 32 + lg * 8) * 2) ^ swzk));
      f32x4 a0 = {0.f, 0.f, 0.f, 0.f}, a1 = {0.f, 0.f, 0.f, 0.f};
#pragma unroll
      for (int kk = 0; kk < 4; ++kk) {
        a0 = __builtin_amdgcn_mfma_f32_16x16x32_bf16(qf[0][kk], kf[kk], a0, 0, 0, 0);
        a1 = __builtin_amdgcn_mfma_f32_16x16x32_bf16(qf[1][kk], kf[kk], a1, 0, 0, 0);
      }
      s0[jb] = a0; s1[jb] = a1;
    }

    char* pw = (char*)&Pl[wave][0];
#pragma unroll
    for (int jb = 0; jb < 4; ++jb) {
      int jg = kv0 + jb * 16 + l15;
#pragma unroll
      for (int rr = 0; rr < 4; ++rr) {
        int rbase = q0 + wave * 32 + lg * 4 + rr;
        float v0 = s0[jb][rr];
        float v1 = s1[jb][rr];
        if (dg && (jg > rbase))      v0 = -__builtin_inff();
        if (dg && (jg > rbase + 16)) v1 = -__builtin_inff();
        float p0 = __builtin_amdgcn_exp2f(v0);   // v_exp_f32 == 2^x; exp2(-inf)=0
        float p1 = __builtin_amdgcn_exp2f(v1);
        lsum[0][rr] += p0;
        lsum[1][rr] += p1;
        int prow0 = lg * 4 + rr;
        int pcol2 = (jb * 16 + l15) * 2;
        *(u16*)(pw + prow0 * 128 + (pcol2 ^ ((prow0 & 7) << 4))) = f2bf(p0);
        int prow1 = prow0 + 16;
        *(u16*)(pw + prow1 * 128 + (pcol2 ^ ((prow1 & 7) << 4))) = f2bf(p1);
      }
    }

    {
      const char* pr = (const char*)&Pl[wave][0];
      bf16x8 pa[2][2];
#pragma unroll
      for (int mf = 0; mf < 2; ++mf) {
        int prow = mf * 16 + l15;
        int pswz = (prow & 7) << 4;
#pragma unroll
        for (int ks = 0; ks < 2; ++ks)
          pa[mf][ks] = *(const bf16x8*)(pr + prow * 128 + (((ks * 32 + lg * 8) * 2) ^ pswz));
      }
#pragma unroll
      for (int db = 0; db < 8; ++db) {
        int d = db * 16 + l15;
        const char* vb = (const char*)&Vl[cur][0] + d * 128;
        int vswz = (d & 7) << 4;
        bf16x8 bb0 = *(const bf16x8*)(vb + (((lg * 8) * 2) ^ vswz));
        bf16x8 bb1 = *(const bf16x8*)(vb + (((32 + lg * 8) * 2) ^ vswz));
        o[0][db] = __builtin_amdgcn_mfma_f32_16x16x32_bf16(pa[0][0], bb0, o[0][db], 0, 0, 0);
        o[0][db] = __builtin_amdgcn_mfma_f32_16x16x32_bf16(pa[0][1], bb1, o[0][db], 0, 0, 0);
        o[1][db] = __builtin_amdgcn_mfma_f32_16x16x32_bf16(pa[1][0], bb0, o[1][db], 0, 0, 0);
        o[1][db] = __builtin_amdgcn_mfma_f32_16x16x32_bf16(pa[1][1], bb1, o[1][db], 0, 0, 0);
      }
    }
    __syncthreads();
  }

#pragma unroll
  for (int off = 1; off < 16; off <<= 1)
#pragma unroll
    for (int mf = 0; mf < 2; ++mf)
#pragma unroll
      for (int rr = 0; rr < 4; ++rr)
        lsum[mf][rr] += __shfl_xor(lsum[mf][rr], off, 64);

  if (cpart < 0) {
#pragma unroll
    for (int mf = 0; mf < 2; ++mf)
#pragma unroll
      for (int db = 0; db < 8; ++db) {
        int col = h * 128 + db * 16 + l15;
#pragma unroll
        for (int rr = 0; rr < 4; ++rr) {
          int row = q0 + wave * 32 + mf * 16 + lg * 4 + rr;
          aout[(size_t)row * HID + col] = f2bf(o[mf][db][rr] / lsum[mf][rr]);
        }
      }
  } else {
    const int slot = (h * 8 + (qt - 8)) * 2 + cpart;
    float* Op = Opart + (size_t)slot * 128 * 128;
#pragma unroll
    for (int mf = 0; mf < 2; ++mf)
#pragma unroll
      for (int db = 0; db < 8; ++db)
#pragma unroll
        for (int rr = 0; rr < 4; ++rr) {
          int row = wave * 32 + mf * 16 + lg * 4 + rr;
          Op[row * 128 + db * 16 + l15] = o[mf][db][rr];
        }
    if (l15 == 0) {
#pragma unroll
      for (int mf = 0; mf < 2; ++mf)
#pragma unroll
        for (int rr = 0; rr < 4; ++rr) {
          int row = wave * 32 + mf * 16 + lg * 4 + rr;
          Lpart[slot * 128 + row] = lsum[mf][rr];
        }
    }
  }
}

// ---------------- combine the two partials per (h, qt>=8) -> aout ----------------
__global__ void attn_reduce_kernel(const float* __restrict__ Opart,
                                   const float* __restrict__ Lpart,
                                   u16* __restrict__ aout) {
  const int b = blockIdx.x;            // 256 = 32 heads x 8 qtiles
  const int h = b >> 3, qi = b & 7;
  const int qt = 8 + qi;
  const int s0 = (h * 8 + qi) * 2, s1 = s0 + 1;
  const int tid = threadIdx.x;
  const int row  = tid >> 1;           // 0..127
  const int half = (tid & 1) * 64;     // 0 or 64

  float inv = 1.0f / (Lpart[s0 * 128 + row] + Lpart[s1 * 128 + row]);

  const float* O0 = Opart + ((size_t)s0 * 128 + row) * 128 + half;
  const float* O1 = Opart + ((size_t)s1 * 128 + row) * 128 + half;
  u16* out = aout + (size_t)(qt * 128 + row) * HID + h * 128 + half;
#pragma unroll
  for (int j = 0; j < 16; ++j) {
    f32x4 a  = *(const f32x4*)(O0 + j * 4);
    f32x4 bb = *(const f32x4*)(O1 + j * 4);
    u16x4 pk;
#pragma unroll
    for (int e = 0; e < 4; ++e) pk[e] = f2bf((a[e] + bb[e]) * inv);
    *(u16x4*)(out + j * 4) = pk;
  }
}

// ---------------- host launch ----------------
extern "C" void kernel_launch(void* const* d_in, const int* in_sizes, int n_in,
                              void* d_out, int out_size, void* d_ws, size_t ws_size,
                              hipStream_t stream) {
  (void)in_sizes; (void)n_in; (void)out_size; (void)ws_size;
  const float* hs  = (const float*)d_in[0];
  const float* q_w = (const float*)d_in[1];
  const float* q_b = (const float*)d_in[2];
  const float* k_w = (const float*)d_in[3];
  const float* k_b = (const float*)d_in[4];
  const float* v_w = (const float*)d_in[5];
  const float* v_b = (const float*)d_in[6];
  const float* o_w = (const float*)d_in[7];
  const int*   pos = (const int*)d_in[8];

  char* ws = (char*)d_ws;
  u16*   xbf   = (u16*)(ws);                          // [2048][4096]   16.78 MB (dead after QKV gemm)
  u16*   wqkv  = (u16*)(ws + 16777216);               // [5120][4096]   41.94 MB (dead after QKV gemm)
  u16*   owbf  = (u16*)(ws + 58720256);               // [4096][4096]   33.55 MB
  float* bias  = (float*)(ws + 92274688);             // [5120]
  u16*   qkv   = (u16*)(ws + 92295168);               // [2048][5120]   20.97 MB
  u16*   vt    = (u16*)(ws + 113266688);              // [512][2048]     2.10 MB
  u16*   aout  = (u16*)(ws + 115363840);              // [2048][4096]   16.78 MB
  // attention partials overlay the dead xbf/wqkv region:
  float* Opart = (float*)(ws);                        // [512][128][128] 33.55 MB
  float* Lpart = (float*)(ws + 33554432);             // [512][128]       0.26 MB

  cvt_all_kernel<<<2048, 256, 0, stream>>>(hs, q_w, k_w, v_w, o_w, xbf, wqkv, owbf);
  biascat_kernel<<<20, 256, 0, stream>>>(q_b, k_b, v_b, bias);

  gemm_qkv_kernel<<<dim3(QKV_N / 160, S_TOK / 128), 256, 0, stream>>>(
      xbf, wqkv, qkv, bias, S_TOK, QKV_N, HID);

  rope_kernel<<<(S_TOK * 36) / 4, 256, 0, stream>>>(qkv, pos);
  vtrans_kernel<<<dim3(16, 64), 256, 0, stream>>>(qkv, vt);

  attn_kernel<<<768, 256, 0, stream>>>(qkv, vt, aout, Opart, Lpart);
  attn_reduce_kernel<<<256, 256, 0, stream>>>(Opart, Lpart, aout);

  gemm128_kernel<0><<<dim3(HID / 128, S_TOK / 128), 256, 0, stream>>>(
      aout, owbf, d_out, S_TOK, HID, HID);
}

// Round 18
// 299.503 us; speedup vs baseline: 1.0156x; 1.0156x over previous
//
#include <hip/hip_runtime.h>
#include <stdint.h>

// Qwen2 attention layer: B=1, S=2048, H=4096, NH=32, NKV=4, HD=128, causal GQA + RoPE.
// Best-known configuration (R13 base): cvt_all(+bias fused) -> QKV gemm (128x320, 256
// blocks, relaxed 1-barrier/tile, 3-deep B dbuf, counted vmcnt) -> RoPE -> V transpose
// -> flash attention (QBLK=128, no-max softmax, KV-split) -> reduce
// -> O gemm (128x128, 512 blocks = 2/CU, fp32 out).

using bf16x8 = __attribute__((ext_vector_type(8))) short;          // MFMA A/B frag (8 bf16, 4 VGPR)
using f32x4  = __attribute__((ext_vector_type(4))) float;          // MFMA C/D frag
using u16    = unsigned short;
using u16x4  = __attribute__((ext_vector_type(4))) unsigned short; // 8B store
using u16x8  = __attribute__((ext_vector_type(8))) unsigned short; // 16B copy type

#define S_TOK   2048
#define HID     4096
#define QKV_N   5120   // 4096 q + 512 k + 512 v
#define K_OFF   4096
#define V_OFF   4608
#define NHEAD   32
#define NKVH    4

__device__ __forceinline__ float bf2f(u16 u) {
  unsigned v = ((unsigned)u) << 16;
  return __builtin_bit_cast(float, v);
}
__device__ __forceinline__ u16 f2bf(float f) {   // round-to-nearest-even
  unsigned u = __builtin_bit_cast(unsigned, f);
  u += 0x7fffu + ((u >> 16) & 1u);
  return (u16)(u >> 16);
}

// ---- fused fp32 -> bf16 convert for all 5 inputs + bias concat (grid-stride) ----
__global__ void cvt_all_kernel(const float* __restrict__ hs, const float* __restrict__ qw,
                               const float* __restrict__ kw, const float* __restrict__ vw,
                               const float* __restrict__ ow,
                               const float* __restrict__ qb, const float* __restrict__ kb,
                               const float* __restrict__ vb,
                               u16* __restrict__ xbf, u16* __restrict__ wqkv,
                               u16* __restrict__ owbf, float* __restrict__ bias) {
  const int gtid = blockIdx.x * 256 + threadIdx.x;
  if (gtid < QKV_N) {  // bias concat (q_b | k_b | v_b)
    float v;
    if (gtid < K_OFF) v = qb[gtid];
    else if (gtid < V_OFF) v = kb[gtid - K_OFF];
    else v = vb[gtid - V_OFF];
    bias[gtid] = v;
  }
  const int nHS = 2097152, nQW = 4194304, nKW = 524288, nVW = 524288, nOW = 4194304;
  const int total = nHS + nQW + nKW + nVW + nOW;   // x4 fp32 elements
  int stride = gridDim.x * blockDim.x;
  for (int i = gtid; i < total; i += stride) {
    const float* s; u16* d; int j = i;
    if (j < nHS) { s = hs; d = xbf; }
    else {
      j -= nHS;
      if (j < nQW) { s = qw; d = wqkv; }
      else {
        j -= nQW;
        if (j < nKW) { s = kw; d = wqkv + 16777216; }
        else {
          j -= nKW;
          if (j < nVW) { s = vw; d = wqkv + 18874368; }
          else { j -= nVW; s = ow; d = owbf; }
        }
      }
    }
    f32x4 v = ((const f32x4*)s)[j];
    union { u16 a[4]; unsigned long long ll; } o;
    o.a[0] = f2bf(v[0]); o.a[1] = f2bf(v[1]); o.a[2] = f2bf(v[2]); o.a[3] = f2bf(v[3]);
    ((unsigned long long*)d)[j] = o.ll;
  }
}

// ---------------- async global->LDS (16B per lane, dest = wave base + lane*16) ----------------
__device__ __forceinline__ void gload_lds16(const void* g, void* l) {
  __builtin_amdgcn_global_load_lds(
      (const __attribute__((address_space(1))) void*)g,
      (__attribute__((address_space(3))) void*)l, 16, 0, 0);
}

// ---------------- QKV GEMM: BM=128, BN=320, grid 256 blocks (1/CU) — R11/R13-verified ----
__global__ __launch_bounds__(512, 2)
void gemm_qkv_kernel(const u16* __restrict__ A, const u16* __restrict__ Bm,
                     u16* __restrict__ C, const float* __restrict__ bias,
                     int M, int N, int K) {
  __shared__ __align__(16) u16 LA[2][8192];    // [2 dbuf][128*64]   32 KB
  __shared__ __align__(16) u16 LB[3][20480];   // [3 dbuf][320*64]  120 KB
  const int tid = threadIdx.x;
  const int w = tid >> 6, lane = tid & 63;
  const int lg = lane >> 4, l15 = lane & 15;
  const int wm = w >> 2, wn = w & 3;

  const int nwg  = gridDim.x * gridDim.y;
  const int orig = blockIdx.y * gridDim.x + blockIdx.x;
  const int cpx  = nwg >> 3;
  const int swz  = (orig & 7) * cpx + (orig >> 3);
  const int bx   = swz % gridDim.x, by = swz / gridDim.x;
  const int m0 = by * 128, n0 = bx * 320;
  const int NT = K >> 6;

  const int  srow  = w * 8 + (lane >> 3);
  const int  sslot = (lane & 7) ^ ((lane >> 3) & 7);
  const u16* As = A  + (size_t)(m0 + srow) * K + sslot * 8;
  const u16* Bs = Bm + (size_t)(n0 + srow) * K + sslot * 8;
  const int  dofs = w * 1024;

  auto stageA = [&](int buf, int t) {
#pragma unroll
    for (int j = 0; j < 2; ++j)
      gload_lds16(As + (size_t)(j * 64) * K + t * 64,
                  (char*)&LA[buf][0] + dofs + j * 8192);
  };
  auto stageB = [&](int buf, int t) {
#pragma unroll
    for (int j = 0; j < 5; ++j)
      gload_lds16(Bs + (size_t)(j * 64) * K + t * 64,
                  (char*)&LB[buf][0] + dofs + j * 8192);
  };

  const int rsw = (l15 & 7) << 4;
  auto ldA = [&](int buf, int kk, bf16x8 (&a)[4]) {
#pragma unroll
    for (int mi = 0; mi < 4; ++mi)
      a[mi] = *(const bf16x8*)((const char*)&LA[buf][0]
              + (wm * 64 + mi * 16 + l15) * 128
              + ((kk * 64 + lg * 16) ^ rsw));
  };
  auto ldB = [&](int buf, int kk, bf16x8 (&b)[5]) {
#pragma unroll
    for (int nf = 0; nf < 5; ++nf)
      b[nf] = *(const bf16x8*)((const char*)&LB[buf][0]
              + (wn * 80 + nf * 16 + l15) * 128
              + ((kk * 64 + lg * 16) ^ rsw));
  };

  f32x4 acc[4][5] = {};
  bf16x8 a[4], b[5];

  auto mfma20 = [&]() {
#pragma unroll
    for (int mi = 0; mi < 4; ++mi)
#pragma unroll
      for (int nf = 0; nf < 5; ++nf)
        acc[mi][nf] = __builtin_amdgcn_mfma_f32_16x16x32_bf16(a[mi], b[nf], acc[mi][nf], 0, 0, 0);
  };

  stageA(0, 0); stageB(0, 0);
  stageA(1, 1); stageB(1, 1);
  asm volatile("s_waitcnt vmcnt(7)" ::: "memory");
  __builtin_amdgcn_s_barrier();

  for (int t = 0; t < NT; ++t) {
    const int bufA = t & 1, bufB = t % 3;
    ldA(bufA, 0, a);
    ldB(bufB, 0, b);
    if (t > 0 && t + 1 < NT) stageA((t + 1) & 1, t + 1);
    if (t + 2 < NT)          stageB((t + 2) % 3, t + 2);
    mfma20();
    ldA(bufA, 1, a);
    ldB(bufB, 1, b);
    mfma20();
    if (t >= NT - 2) asm volatile("s_waitcnt vmcnt(0)" ::: "memory");
    else             asm volatile("s_waitcnt vmcnt(5)" ::: "memory");
    __builtin_amdgcn_s_barrier();
  }

#pragma unroll
  for (int mi = 0; mi < 4; ++mi)
#pragma unroll
    for (int nf = 0; nf < 5; ++nf) {
      const int row0 = m0 + wm * 64 + mi * 16 + lg * 4;
      const int cc   = n0 + wn * 80 + nf * 16 + l15;
      const float bv = bias[cc];
#pragma unroll
      for (int rI = 0; rI < 4; ++rI)
        C[(size_t)(row0 + rI) * N + cc] = f2bf(acc[mi][nf][rI] + bv);
    }
}

// ---------------- O GEMM: BM=128, BN=128, 256 thr, grid 512 blocks = 2/CU (R13) ----
template <int BF16OUT>
__global__ __launch_bounds__(256, 2)
void gemm128_kernel(const u16* __restrict__ A, const u16* __restrict__ Bm,
                    void* __restrict__ C, int M, int N, int K) {
  __shared__ __align__(16) u16 LA[2][8192];    // [2 dbuf][128*64]  32 KB
  __shared__ __align__(16) u16 LB[3][8192];    // [3 dbuf][128*64]  48 KB
  const int tid = threadIdx.x;
  const int w = tid >> 6, lane = tid & 63;     // w in 0..3
  const int lg = lane >> 4, l15 = lane & 15;
  const int wm = w >> 1, wn = w & 1;

  const int nwg  = gridDim.x * gridDim.y;      // 512
  const int orig = blockIdx.y * gridDim.x + blockIdx.x;
  const int cpx  = nwg >> 3;
  const int swz  = (orig & 7) * cpx + (orig >> 3);
  const int bx   = swz % gridDim.x, by = swz / gridDim.x;
  const int m0 = by * 128, n0 = bx * 128;
  const int NT = K >> 6;

  const int  srow  = w * 16 + (lane >> 3);
  const int  sslot = (lane & 7) ^ ((lane >> 3) & 7);
  const u16* As = A  + (size_t)(m0 + srow) * K + sslot * 8;
  const u16* Bs = Bm + (size_t)(n0 + srow) * K + sslot * 8;
  const int  dofs = w * 2048;

  auto stageA = [&](int buf, int t) {
#pragma unroll
    for (int j = 0; j < 2; ++j)
#pragma unroll
      for (int sub = 0; sub < 2; ++sub)
        gload_lds16(As + (size_t)(j * 64 + sub * 8) * K + t * 64,
                    (char*)&LA[buf][0] + j * 8192 + dofs + sub * 1024);
  };
  auto stageB = [&](int buf, int t) {
#pragma unroll
    for (int j = 0; j < 2; ++j)
#pragma unroll
      for (int sub = 0; sub < 2; ++sub)
        gload_lds16(Bs + (size_t)(j * 64 + sub * 8) * K + t * 64,
                    (char*)&LB[buf][0] + j * 8192 + dofs + sub * 1024);
  };

  const int rsw = (l15 & 7) << 4;
  auto ldA = [&](int buf, bf16x8 (&a)[2][4]) {
#pragma unroll
    for (int kk = 0; kk < 2; ++kk)
#pragma unroll
      for (int mi = 0; mi < 4; ++mi)
        a[kk][mi] = *(const bf16x8*)((const char*)&LA[buf][0]
                    + (wm * 64 + mi * 16 + l15) * 128
                    + ((kk * 64 + lg * 16) ^ rsw));
  };
  auto ldB = [&](int buf, bf16x8 (&b)[2][4]) {
#pragma unroll
    for (int kk = 0; kk < 2; ++kk)
#pragma unroll
      for (int nf = 0; nf < 4; ++nf)
        b[kk][nf] = *(const bf16x8*)((const char*)&LB[buf][0]
                    + (wn * 64 + nf * 16 + l15) * 128
                    + ((kk * 64 + lg * 16) ^ rsw));
  };

  f32x4 acc[4][4] = {};   // [mi][nf]
  bf16x8 a[2][4], b[2][4];

  auto mfma32 = [&]() {
#pragma unroll
    for (int kk = 0; kk < 2; ++kk)
#pragma unroll
      for (int mi = 0; mi < 4; ++mi)
#pragma unroll
        for (int nf = 0; nf < 4; ++nf)
          acc[mi][nf] = __builtin_amdgcn_mfma_f32_16x16x32_bf16(a[kk][mi], b[kk][nf], acc[mi][nf], 0, 0, 0);
  };

  stageA(0, 0); stageB(0, 0);
  stageA(1, 1); stageB(1, 1);
  asm volatile("s_waitcnt vmcnt(8)" ::: "memory");
  __builtin_amdgcn_s_barrier();

  for (int t = 0; t < NT; ++t) {
    const int bufA = t & 1, bufB = t % 3;
    ldA(bufA, a);
    ldB(bufB, b);
    if (t > 0 && t + 1 < NT) stageA((t + 1) & 1, t + 1);
    if (t + 2 < NT)          stageB((t + 2) % 3, t + 2);
    mfma32();
    if (t >= NT - 2) asm volatile("s_waitcnt vmcnt(0)" ::: "memory");
    else             asm volatile("s_waitcnt vmcnt(4)" ::: "memory");
    __builtin_amdgcn_s_barrier();
  }

#pragma unroll
  for (int mi = 0; mi < 4; ++mi)
#pragma unroll
    for (int nf = 0; nf < 4; ++nf) {
      const int row0 = m0 + wm * 64 + mi * 16 + lg * 4;
      const int cc   = n0 + wn * 64 + nf * 16 + l15;
#pragma unroll
      for (int rI = 0; rI < 4; ++rI) {
        float v = acc[mi][nf][rI];
        if (BF16OUT) ((u16*)C)[(size_t)(row0 + rI) * N + cc] = f2bf(v);
        else         ((float*)C)[(size_t)(row0 + rI) * N + cc] = v;
      }
    }
}

// ---------------- RoPE in-place on q,k regions of qkv; folds 1/sqrt(HD) into q ----------------
__global__ void rope_kernel(u16* __restrict__ qkv, const int* __restrict__ pos_ids) {
  const int tid  = threadIdx.x;
  const int gid  = blockIdx.x * 4 + (tid >> 6);   // (s, head) pair; 2048*36 total
  const int lane = tid & 63;                       // d in [0,64)
  const int s = gid / 36, hh = gid - s * 36;       // hh: 0..31 q heads, 32..35 k heads
  const float pos = (float)pos_ids[s];
  const float inv = exp2f((float)lane * -0.20762050593f);  // 10000^(-d/64)
  float sn, cs;
  sincosf(pos * inv, &sn, &cs);
  size_t base = (size_t)s * QKV_N + (hh < 32 ? hh * 128 : K_OFF + (hh - 32) * 128);
  float x1 = bf2f(qkv[base + lane]);
  float x2 = bf2f(qkv[base + lane + 64]);
  float o1 = x1 * cs - x2 * sn;
  float o2 = x2 * cs + x1 * sn;
  if (hh < 32) { o1 *= 0.08838834764831845f; o2 *= 0.08838834764831845f; }
  qkv[base + lane]      = f2bf(o1);
  qkv[base + lane + 64] = f2bf(o2);
}

// ---------------- V transpose: qkv v-cols [2048][512] -> vt [512][2048] ----------------
__global__ void vtrans_kernel(const u16* __restrict__ qkv, u16* __restrict__ vt) {
  __shared__ u16 t[32][33];
  const int tx = threadIdx.x & 31, ty = threadIdx.x >> 5;  // 32x8
  const int bc = blockIdx.x;  // 16 col tiles (512/32)
  const int bs = blockIdx.y;  // 64 row tiles (2048/32)
#pragma unroll
  for (int i = 0; i < 4; ++i)
    t[ty + i * 8][tx] = qkv[(size_t)(bs * 32 + ty + i * 8) * QKV_N + V_OFF + bc * 32 + tx];
  __syncthreads();
#pragma unroll
  for (int i = 0; i < 4; ++i)
    vt[(size_t)(bc * 32 + ty + i * 8) * S_TOK + bs * 32 + tx] = t[tx][ty + i * 8];
}

// ---------------- Flash attention: QBLK=128, no-max softmax, KV-split (R11/R13) --------
__global__ __launch_bounds__(256, 2)
void attn_kernel(const u16* __restrict__ qkv, const u16* __restrict__ vt,
                 u16* __restrict__ aout, float* __restrict__ Opart,
                 float* __restrict__ Lpart) {
  __shared__ __align__(16) u16 Kl[2][64 * 128];   // K tile, rows 256B, chunk-swizzled
  __shared__ __align__(16) u16 Vl[2][128 * 64];   // V^T tile, rows 128B, chunk-swizzled
  __shared__ __align__(16) u16 Pl[4][32 * 64];    // per-wave P (32x64), rows 128B
  const int tid = threadIdx.x, wave = tid >> 6, lane = tid & 63;
  const int lg = lane >> 4, l15 = lane & 15;

  const int bid  = blockIdx.x;
  const int xcd  = bid & 7;
  const int idx  = bid >> 3;
  const int kvh  = xcd >> 1;
  const int item = idx * 2 + (xcd & 1);
  const int h    = (kvh << 3) + item / 24;
  const int r    = item % 24;

  int qt, t0, t1, cpart;
  bool diag;
  if (r < 8)       { qt = r;     t0 = 0;  t1 = 2 * r + 1;  cpart = -1; diag = true;  }
  else if (r < 16) { qt = r;     t0 = 0;  t1 = 15;         cpart = 0;  diag = false; }
  else             { qt = r - 8; t0 = 16; t1 = 2 * qt + 1; cpart = 1;  diag = true;  }
  const int q0 = qt * 128;

  bf16x8 qf[2][4];
#pragma unroll
  for (int mf = 0; mf < 2; ++mf) {
    const u16* qp = qkv + (size_t)(q0 + wave * 32 + mf * 16 + l15) * QKV_N + h * 128 + lg * 8;
#pragma unroll
    for (int kk = 0; kk < 4; ++kk) qf[mf][kk] = *(const bf16x8*)(qp + kk * 32);
  }

  const u16* kp[4];
  const u16* vp[4];
  const int kc0 = wave * 4;
#pragma unroll
  for (int i = 0; i < 4; ++i) {
    int krow = (kc0 + i) * 4 + (lane >> 4);
    int kch  = lane & 15;
    kp[i] = qkv + K_OFF + kvh * 128 + (size_t)krow * QKV_N + ((kch ^ (krow & 7)) * 8);
    int vrow = (kc0 + i) * 8 + (lane >> 3);     // d index 0..127
    int vch  = lane & 7;
    vp[i] = vt + (size_t)(kvh * 128 + vrow) * S_TOK + ((vch ^ (vrow & 7)) * 8);
  }

  f32x4 o[2][8];
#pragma unroll
  for (int mf = 0; mf < 2; ++mf)
#pragma unroll
    for (int i = 0; i < 8; ++i) o[mf][i] = f32x4{0.f, 0.f, 0.f, 0.f};
  float lsum[2][4] = {};

#pragma unroll
  for (int i = 0; i < 4; ++i) {
    gload_lds16(kp[i] + (size_t)t0 * 64 * QKV_N, &Kl[t0 & 1][(kc0 + i) * 512]);
    gload_lds16(vp[i] + t0 * 64,                 &Vl[t0 & 1][(kc0 + i) * 512]);
  }
  __syncthreads();

  for (int t = t0; t <= t1; ++t) {
    const int cur = t & 1;
    if (t < t1) {
      const size_t koff = (size_t)(t + 1) * 64 * QKV_N;
      const int    voff = (t + 1) * 64;
#pragma unroll
      for (int i = 0; i < 4; ++i) {
        gload_lds16(kp[i] + koff, &Kl[cur ^ 1][(kc0 + i) * 512]);
        gload_lds16(vp[i] + voff, &Vl[cur ^ 1][(kc0 + i) * 512]);
      }
    }
    const int kv0 = t * 64;
    const bool dg = diag && (t >= 2 * qt);   // last two tiles straddle the diagonal

    f32x4 s0[4], s1[4];
#pragma unroll
    for (int jb = 0; jb < 4; ++jb) {
      int j = jb * 16 + l15;
      const char* kb = (const char*)&Kl[cur][0] + j * 256;
      int swzk = (j & 7) << 4;
      bf16x8 kf[4];
#pragma unroll
      for (int kk = 0; kk < 4; ++kk)
        kf[kk] = *(const bf16x8*)(kb + (((kk * 32 + lg * 8) * 2) ^ swzk));
      f32x4 a0 = {0.f, 0.f, 0.f, 0.f}, a1 = {0.f, 0.f, 0.f, 0.f};
#pragma unroll
      for (int kk = 0; kk < 4; ++kk) {
        a0 = __builtin_amdgcn_mfma_f32_16x16x32_bf16(qf[0][kk], kf[kk], a0, 0, 0, 0);
        a1 = __builtin_amdgcn_mfma_f32_16x16x32_bf16(qf[1][kk], kf[kk], a1, 0, 0, 0);
      }
      s0[jb] = a0; s1[jb] = a1;
    }

    char* pw = (char*)&Pl[wave][0];
#pragma unroll
    for (int jb = 0; jb < 4; ++jb) {
      int jg = kv0 + jb * 16 + l15;
#pragma unroll
      for (int rr = 0; rr < 4; ++rr) {
        int rbase = q0 + wave * 32 + lg * 4 + rr;
        float v0 = s0[jb][rr];
        float v1 = s1[jb][rr];
        if (dg && (jg > rbase))      v0 = -__builtin_inff();
        if (dg && (jg > rbase + 16)) v1 = -__builtin_inff();
        float p0 = __expf(v0);
        float p1 = __expf(v1);
        lsum[0][rr] += p0;
        lsum[1][rr] += p1;
        int prow0 = lg * 4 + rr;
        int pcol2 = (jb * 16 + l15) * 2;
        *(u16*)(pw + prow0 * 128 + (pcol2 ^ ((prow0 & 7) << 4))) = f2bf(p0);
        int prow1 = prow0 + 16;
        *(u16*)(pw + prow1 * 128 + (pcol2 ^ ((prow1 & 7) << 4))) = f2bf(p1);
      }
    }

    {
      const char* pr = (const char*)&Pl[wave][0];
      bf16x8 pa[2][2];
#pragma unroll
      for (int mf = 0; mf < 2; ++mf) {
        int prow = mf * 16 + l15;
        int pswz = (prow & 7) << 4;
#pragma unroll
        for (int ks = 0; ks < 2; ++ks)
          pa[mf][ks] = *(const bf16x8*)(pr + prow * 128 + (((ks * 32 + lg * 8) * 2) ^ pswz));
      }
#pragma unroll
      for (int db = 0; db < 8; ++db) {
        int d = db * 16 + l15;
        const char* vb = (const char*)&Vl[cur][0] + d * 128;
        int vswz = (d & 7) << 4;
        bf16x8 bb0 = *(const bf16x8*)(vb + (((lg * 8) * 2) ^ vswz));
        bf16x8 bb1 = *(const bf16x8*)(vb + (((32 + lg * 8) * 2) ^ vswz));
        o[0][db] = __builtin_amdgcn_mfma_f32_16x16x32_bf16(pa[0][0], bb0, o[0][db], 0, 0, 0);
        o[0][db] = __builtin_amdgcn_mfma_f32_16x16x32_bf16(pa[0][1], bb1, o[0][db], 0, 0, 0);
        o[1][db] = __builtin_amdgcn_mfma_f32_16x16x32_bf16(pa[1][0], bb0, o[1][db], 0, 0, 0);
        o[1][db] = __builtin_amdgcn_mfma_f32_16x16x32_bf16(pa[1][1], bb1, o[1][db], 0, 0, 0);
      }
    }
    __syncthreads();
  }

#pragma unroll
  for (int off = 1; off < 16; off <<= 1)
#pragma unroll
    for (int mf = 0; mf < 2; ++mf)
#pragma unroll
      for (int rr = 0; rr < 4; ++rr)
        lsum[mf][rr] += __shfl_xor(lsum[mf][rr], off, 64);

  if (cpart < 0) {
#pragma unroll
    for (int mf = 0; mf < 2; ++mf)
#pragma unroll
      for (int db = 0; db < 8; ++db) {
        int col = h * 128 + db * 16 + l15;
#pragma unroll
        for (int rr = 0; rr < 4; ++rr) {
          int row = q0 + wave * 32 + mf * 16 + lg * 4 + rr;
          aout[(size_t)row * HID + col] = f2bf(o[mf][db][rr] / lsum[mf][rr]);
        }
      }
  } else {
    const int slot = (h * 8 + (qt - 8)) * 2 + cpart;
    float* Op = Opart + (size_t)slot * 128 * 128;
#pragma unroll
    for (int mf = 0; mf < 2; ++mf)
#pragma unroll
      for (int db = 0; db < 8; ++db)
#pragma unroll
        for (int rr = 0; rr < 4; ++rr) {
          int row = wave * 32 + mf * 16 + lg * 4 + rr;
          Op[row * 128 + db * 16 + l15] = o[mf][db][rr];
        }
    if (l15 == 0) {
#pragma unroll
      for (int mf = 0; mf < 2; ++mf)
#pragma unroll
        for (int rr = 0; rr < 4; ++rr) {
          int row = wave * 32 + mf * 16 + lg * 4 + rr;
          Lpart[slot * 128 + row] = lsum[mf][rr];
        }
    }
  }
}

// ---------------- combine the two partials per (h, qt>=8) -> aout ----------------
__global__ void attn_reduce_kernel(const float* __restrict__ Opart,
                                   const float* __restrict__ Lpart,
                                   u16* __restrict__ aout) {
  const int b = blockIdx.x;            // 256 = 32 heads x 8 qtiles
  const int h = b >> 3, qi = b & 7;
  const int qt = 8 + qi;
  const int s0 = (h * 8 + qi) * 2, s1 = s0 + 1;
  const int tid = threadIdx.x;
  const int row  = tid >> 1;           // 0..127
  const int half = (tid & 1) * 64;     // 0 or 64

  float inv = 1.0f / (Lpart[s0 * 128 + row] + Lpart[s1 * 128 + row]);

  const float* O0 = Opart + ((size_t)s0 * 128 + row) * 128 + half;
  const float* O1 = Opart + ((size_t)s1 * 128 + row) * 128 + half;
  u16* out = aout + (size_t)(qt * 128 + row) * HID + h * 128 + half;
#pragma unroll
  for (int j = 0; j < 16; ++j) {
    f32x4 a  = *(const f32x4*)(O0 + j * 4);
    f32x4 bb = *(const f32x4*)(O1 + j * 4);
    u16x4 pk;
#pragma unroll
    for (int e = 0; e < 4; ++e) pk[e] = f2bf((a[e] + bb[e]) * inv);
    *(u16x4*)(out + j * 4) = pk;
  }
}

// ---------------- host launch ----------------
extern "C" void kernel_launch(void* const* d_in, const int* in_sizes, int n_in,
                              void* d_out, int out_size, void* d_ws, size_t ws_size,
                              hipStream_t stream) {
  (void)in_sizes; (void)n_in; (void)out_size; (void)ws_size;
  const float* hs  = (const float*)d_in[0];
  const float* q_w = (const float*)d_in[1];
  const float* q_b = (const float*)d_in[2];
  const float* k_w = (const float*)d_in[3];
  const float* k_b = (const float*)d_in[4];
  const float* v_w = (const float*)d_in[5];
  const float* v_b = (const float*)d_in[6];
  const float* o_w = (const float*)d_in[7];
  const int*   pos = (const int*)d_in[8];

  char* ws = (char*)d_ws;
  u16*   xbf   = (u16*)(ws);                          // [2048][4096]   16.78 MB (dead after QKV gemm)
  u16*   wqkv  = (u16*)(ws + 16777216);               // [5120][4096]   41.94 MB (dead after QKV gemm)
  u16*   owbf  = (u16*)(ws + 58720256);               // [4096][4096]   33.55 MB
  float* bias  = (float*)(ws + 92274688);             // [5120]
  u16*   qkv   = (u16*)(ws + 92295168);               // [2048][5120]   20.97 MB
  u16*   vt    = (u16*)(ws + 113266688);              // [512][2048]     2.10 MB
  u16*   aout  = (u16*)(ws + 115363840);              // [2048][4096]   16.78 MB
  // attention partials overlay the dead xbf/wqkv region:
  float* Opart = (float*)(ws);                        // [512][128][128] 33.55 MB
  float* Lpart = (float*)(ws + 33554432);             // [512][128]       0.26 MB

  cvt_all_kernel<<<2048, 256, 0, stream>>>(hs, q_w, k_w, v_w, o_w,
                                           q_b, k_b, v_b, xbf, wqkv, owbf, bias);

  gemm_qkv_kernel<<<dim3(QKV_N / 320, S_TOK / 128), 512, 0, stream>>>(
      xbf, wqkv, qkv, bias, S_TOK, QKV_N, HID);

  rope_kernel<<<(S_TOK * 36) / 4, 256, 0, stream>>>(qkv, pos);
  vtrans_kernel<<<dim3(16, 64), 256, 0, stream>>>(qkv, vt);

  attn_kernel<<<768, 256, 0, stream>>>(qkv, vt, aout, Opart, Lpart);
  attn_reduce_kernel<<<256, 256, 0, stream>>>(Opart, Lpart, aout);

  gemm128_kernel<0><<<dim3(HID / 128, S_TOK / 128), 256, 0, stream>>>(
      aout, owbf, d_out, S_TOK, HID, HID);
}